// Round 1
// baseline (1076.487 us; speedup 1.0000x reference)
//
#include <hip/hip_runtime.h>
#include <math.h>

// Transformer-XL style relative-position MHSA, f32 baseline.
// B=4 S=1024 D=1024 H=16 HD=64 M=128.
// Pipeline: gen_remb -> gemm(Q) -> gemm(K) -> gemm(V) -> attn -> gemm(out).
// ws layout (floats): remb[257*64] | Q[B*S*D] | K | V | AO   (~67 MB)

#define BB 4
#define SS 1024
#define DD 1024
#define HH 16
#define HDIM 64
#define RREL 257
#define SCALE 0.125f

// ---------------------------------------------------------------- rel_emb gen
__global__ void gen_remb(float* __restrict__ remb) {
  const int r = blockIdx.x;      // 0..256
  const int d = threadIdx.x;     // 0..63
  const int pair = d >> 1;
  // inv_freq = 10000^(-2*pair/64) = 2^(-(2*pair/64)*log2(10000))
  const float inv_freq = exp2f(-((float)(2 * pair) / 64.0f) * 13.287712379549449f);
  const float arg = (float)(r - 128) * inv_freq;
  const float val = (d & 1) ? cosf(arg) : sinf(arg);
  remb[r * HDIM + d] = val;
}

// ---------------------------------------------------------------- dense GEMM
// C[MROWS x 1024] = A[MROWS x 1024] @ W[1024 x 1024] + bias (row-major all)
__global__ __launch_bounds__(256) void gemm_bias(
    const float* __restrict__ A, const float* __restrict__ W,
    const float* __restrict__ bias, float* __restrict__ C) {
  __shared__ float As[16][68];  // [k][m], 68-pad -> aligned b128 rows
  __shared__ float Bs[16][68];  // [k][n]
  const int tid = threadIdx.x;
  const int bm = blockIdx.y * 64;
  const int bn = blockIdx.x * 64;
  const int ty = tid >> 4, tx = tid & 15;
  const int alr = tid >> 2;            // 0..63
  const int alc = (tid & 3) << 2;      // 0,4,8,12
  const int blr = tid >> 4;            // 0..15
  const int blc = (tid & 15) << 2;     // 0..60
  float acc[4][4] = {};
  for (int k0 = 0; k0 < DD; k0 += 16) {
    float4 a4 = *reinterpret_cast<const float4*>(&A[(size_t)(bm + alr) * DD + k0 + alc]);
    float4 b4 = *reinterpret_cast<const float4*>(&W[(size_t)(k0 + blr) * DD + bn + blc]);
    As[alc + 0][alr] = a4.x;
    As[alc + 1][alr] = a4.y;
    As[alc + 2][alr] = a4.z;
    As[alc + 3][alr] = a4.w;
    *reinterpret_cast<float4*>(&Bs[blr][blc]) = b4;
    __syncthreads();
#pragma unroll
    for (int kk = 0; kk < 16; ++kk) {
      float4 av = *reinterpret_cast<const float4*>(&As[kk][ty * 4]);
      float4 bv = *reinterpret_cast<const float4*>(&Bs[kk][tx * 4]);
      float a[4] = {av.x, av.y, av.z, av.w};
      float b[4] = {bv.x, bv.y, bv.z, bv.w};
#pragma unroll
      for (int i = 0; i < 4; ++i)
#pragma unroll
        for (int j = 0; j < 4; ++j)
          acc[i][j] = fmaf(a[i], b[j], acc[i][j]);
    }
    __syncthreads();
  }
#pragma unroll
  for (int i = 0; i < 4; ++i) {
    const int row = bm + ty * 4 + i;
    const int col = bn + tx * 4;
    float4 o;
    o.x = acc[i][0] + bias[col + 0];
    o.y = acc[i][1] + bias[col + 1];
    o.z = acc[i][2] + bias[col + 2];
    o.w = acc[i][3] + bias[col + 3];
    *reinterpret_cast<float4*>(&C[(size_t)row * DD + col]) = o;
  }
}

// ---------------------------------------------------------------- attention
// One block per (b, h, 64-row i-tile). Flash-style online softmax over 16
// j-tiles of 64. rel scores via per-row rel_all precomputed into LDS.
__global__ __launch_bounds__(256) void attn_kernel(
    const float* __restrict__ Q, const float* __restrict__ K,
    const float* __restrict__ V, const float* __restrict__ remb,
    const float* __restrict__ ub, const float* __restrict__ vb,
    float* __restrict__ AO) {
  __shared__ float qu_t[64][68];   // [d][i]  (q + u), transposed
  __shared__ float k_t[64][68];    // [d][j]  transposed
  __shared__ float v_s[64][68];    // [j][d]
  __shared__ float p_t[64][68];    // [j][i]  transposed P
  __shared__ float rel_s[64][RREL];// [i][r]
  __shared__ float w_s[64];        // v - u

  const int tid = threadIdx.x;
  const int it = blockIdx.x, h = blockIdx.y, b = blockIdx.z;
  const int i0 = it * 64;
  const int ty = tid >> 4, tx = tid & 15;
  const size_t base = (size_t)b * SS * DD + (size_t)h * HDIM;

  // stage Q tile (transposed, +u)
#pragma unroll
  for (int p = 0; p < 4; ++p) {
    const int flat = p * 1024 + tid * 4;
    const int il = flat >> 6;
    const int dd = flat & 63;
    float4 q4 = *reinterpret_cast<const float4*>(&Q[base + (size_t)(i0 + il) * DD + dd]);
    float4 u4 = *reinterpret_cast<const float4*>(&ub[h * HDIM + dd]);
    qu_t[dd + 0][il] = q4.x + u4.x;
    qu_t[dd + 1][il] = q4.y + u4.y;
    qu_t[dd + 2][il] = q4.z + u4.z;
    qu_t[dd + 3][il] = q4.w + u4.w;
  }
  if (tid < 64) w_s[tid] = vb[h * HDIM + tid] - ub[h * HDIM + tid];
  __syncthreads();

  // rel_all prologue: rel_s[i][r] = scale * (q+v)[i] . remb[r]
  {
    const int il = tid & 63;
    const int rq = tid >> 6;
    float qv[64];
#pragma unroll
    for (int dd = 0; dd < 64; ++dd) qv[dd] = qu_t[dd][il] + w_s[dd];
    for (int r = rq; r < RREL; r += 4) {
      float acc = 0.f;
#pragma unroll
      for (int d4 = 0; d4 < 16; ++d4) {
        float4 e4 = *reinterpret_cast<const float4*>(&remb[r * HDIM + d4 * 4]);
        acc = fmaf(qv[d4 * 4 + 0], e4.x, acc);
        acc = fmaf(qv[d4 * 4 + 1], e4.y, acc);
        acc = fmaf(qv[d4 * 4 + 2], e4.z, acc);
        acc = fmaf(qv[d4 * 4 + 3], e4.w, acc);
      }
      rel_s[il][r] = acc * SCALE;
    }
  }

  float m[4], l[4], o[4][4];
#pragma unroll
  for (int i = 0; i < 4; ++i) {
    m[i] = -3.0e38f;
    l[i] = 0.f;
#pragma unroll
    for (int j = 0; j < 4; ++j) o[i][j] = 0.f;
  }
  __syncthreads();

  for (int jt = 0; jt < 16; ++jt) {
    const int j0 = jt * 64;
    // stage K (transposed) and V
#pragma unroll
    for (int p = 0; p < 4; ++p) {
      const int flat = p * 1024 + tid * 4;
      const int jl = flat >> 6;
      const int dd = flat & 63;
      float4 k4 = *reinterpret_cast<const float4*>(&K[base + (size_t)(j0 + jl) * DD + dd]);
      k_t[dd + 0][jl] = k4.x;
      k_t[dd + 1][jl] = k4.y;
      k_t[dd + 2][jl] = k4.z;
      k_t[dd + 3][jl] = k4.w;
      float4 v4 = *reinterpret_cast<const float4*>(&V[base + (size_t)(j0 + jl) * DD + dd]);
      *reinterpret_cast<float4*>(&v_s[jl][dd]) = v4;
    }
    __syncthreads();

    // scores: S = (q+u) . k^T
    float s[4][4] = {};
#pragma unroll 16
    for (int dd = 0; dd < 64; ++dd) {
      float4 av = *reinterpret_cast<const float4*>(&qu_t[dd][ty * 4]);
      float4 bv4 = *reinterpret_cast<const float4*>(&k_t[dd][tx * 4]);
      float a[4] = {av.x, av.y, av.z, av.w};
      float bb[4] = {bv4.x, bv4.y, bv4.z, bv4.w};
#pragma unroll
      for (int ii = 0; ii < 4; ++ii)
#pragma unroll
        for (int jj = 0; jj < 4; ++jj)
          s[ii][jj] = fmaf(a[ii], bb[jj], s[ii][jj]);
    }

    // rel add + online softmax (row = 16 consecutive lanes: same ty, tx 0..15)
#pragma unroll
    for (int ii = 0; ii < 4; ++ii) {
      const int il = ty * 4 + ii;
      const int ig = i0 + il;
      float sv[4];
      float smax = -3.0e38f;
#pragma unroll
      for (int jj = 0; jj < 4; ++jj) {
        const int jg = j0 + tx * 4 + jj;
        int ro = jg - ig;
        ro = ro < -128 ? -128 : (ro > 128 ? 128 : ro);
        const float val = fmaf(s[ii][jj], SCALE, rel_s[il][ro + 128]);
        sv[jj] = val;
        smax = fmaxf(smax, val);
      }
#pragma unroll
      for (int mk = 1; mk < 16; mk <<= 1)
        smax = fmaxf(smax, __shfl_xor(smax, mk, 16));
      const float m_new = fmaxf(m[ii], smax);
      const float alpha = __expf(m[ii] - m_new);
      float tsum = 0.f;
      float pv[4];
#pragma unroll
      for (int jj = 0; jj < 4; ++jj) {
        pv[jj] = __expf(sv[jj] - m_new);
        tsum += pv[jj];
      }
#pragma unroll
      for (int mk = 1; mk < 16; mk <<= 1)
        tsum += __shfl_xor(tsum, mk, 16);
      l[ii] = l[ii] * alpha + tsum;
      m[ii] = m_new;
#pragma unroll
      for (int jj = 0; jj < 4; ++jj) {
        o[ii][jj] *= alpha;
        p_t[tx * 4 + jj][il] = pv[jj];
      }
    }
    __syncthreads();

    // PV: o += P . V
#pragma unroll 8
    for (int j = 0; j < 64; ++j) {
      float4 av = *reinterpret_cast<const float4*>(&p_t[j][ty * 4]);
      float4 bv4 = *reinterpret_cast<const float4*>(&v_s[j][tx * 4]);
      float a[4] = {av.x, av.y, av.z, av.w};
      float bb[4] = {bv4.x, bv4.y, bv4.z, bv4.w};
#pragma unroll
      for (int ii = 0; ii < 4; ++ii)
#pragma unroll
        for (int jj = 0; jj < 4; ++jj)
          o[ii][jj] = fmaf(a[ii], bb[jj], o[ii][jj]);
    }
    __syncthreads();
  }

  // epilogue: normalize + store
#pragma unroll
  for (int ii = 0; ii < 4; ++ii) {
    const float inv_l = 1.0f / l[ii];
    float4 o4;
    o4.x = o[ii][0] * inv_l;
    o4.y = o[ii][1] * inv_l;
    o4.z = o[ii][2] * inv_l;
    o4.w = o[ii][3] * inv_l;
    *reinterpret_cast<float4*>(&AO[base + (size_t)(i0 + ty * 4 + ii) * DD + tx * 4]) = o4;
  }
}

// ---------------------------------------------------------------- launcher
extern "C" void kernel_launch(void* const* d_in, const int* in_sizes, int n_in,
                              void* d_out, int out_size, void* d_ws, size_t ws_size,
                              hipStream_t stream) {
  const float* x  = (const float*)d_in[0];
  const float* Wq = (const float*)d_in[1];
  const float* bq = (const float*)d_in[2];
  const float* Wk = (const float*)d_in[3];
  const float* bk = (const float*)d_in[4];
  const float* Wv = (const float*)d_in[5];
  const float* bv = (const float*)d_in[6];
  const float* Wo = (const float*)d_in[7];
  const float* bo = (const float*)d_in[8];
  const float* u  = (const float*)d_in[9];
  const float* v  = (const float*)d_in[10];
  float* out = (float*)d_out;

  float* ws = (float*)d_ws;
  const size_t NTOK = (size_t)BB * SS * DD;  // 4M floats
  float* remb = ws;              // 257*64 = 16448 floats
  float* Qb = ws + 16448;
  float* Kb = Qb + NTOK;
  float* Vb = Kb + NTOK;
  float* AO = Vb + NTOK;

  gen_remb<<<dim3(RREL), dim3(64), 0, stream>>>(remb);

  dim3 ggrid(DD / 64, (BB * SS) / 64);
  gemm_bias<<<ggrid, 256, 0, stream>>>(x, Wq, bq, Qb);
  gemm_bias<<<ggrid, 256, 0, stream>>>(x, Wk, bk, Kb);
  gemm_bias<<<ggrid, 256, 0, stream>>>(x, Wv, bv, Vb);

  attn_kernel<<<dim3(SS / 64, HH, BB), 256, 0, stream>>>(Qb, Kb, Vb, remb, u, v, AO);

  gemm_bias<<<ggrid, 256, 0, stream>>>(AO, Wo, bo, out);
}

// Round 5
// 161.538 us; speedup vs baseline: 6.6640x; 6.6640x over previous
//
#include <hip/hip_runtime.h>
#include <math.h>

// Transformer-XL relative-position MHSA, bf16 MFMA pipeline.
// B=4 S=1024 D=1024 H=16 HD=64 M=128.
// gen_remb -> conv_x -> conv_w(transpose) -> fused QKV MFMA gemm
//   -> MFMA flash attention (rel via MFMA + f16 LDS table) -> final MFMA gemm.

#define BB 4
#define SS 1024
#define DD 1024
#define HH 16
#define HDIM 64
#define SCALE 0.125f

typedef __attribute__((ext_vector_type(8))) short short8;
typedef __attribute__((ext_vector_type(4))) float f32x4;
typedef __attribute__((ext_vector_type(4))) unsigned short us4;
typedef unsigned short u16;

#define MFMA __builtin_amdgcn_mfma_f32_16x16x32_bf16

__device__ __forceinline__ float b2f(u16 v) {
  return __uint_as_float((unsigned)v << 16);
}
__device__ __forceinline__ u16 f2b(float f) {
  unsigned u = __float_as_uint(f);
  return (u16)((u + 0x7FFF + ((u >> 16) & 1)) >> 16);  // RNE
}

// ---------------------------------------------------------------- rel_emb gen
// remb bf16 [272][64]; rows 257..271 zero (pad for MFMA frag reads)
__global__ void gen_remb(u16* __restrict__ remb) {
  const int r = blockIdx.x, d = threadIdx.x;
  float val = 0.f;
  if (r < 257) {
    const int pair = d >> 1;
    const float inv_freq = exp2f(-((float)(2 * pair) / 64.0f) * 13.287712379549449f);
    const float arg = (float)(r - 128) * inv_freq;
    val = (d & 1) ? cosf(arg) : sinf(arg);
  }
  remb[r * 64 + d] = f2b(val);
}

// ---------------------------------------------------------------- conversions
__global__ __launch_bounds__(256) void conv_x(const float* __restrict__ x,
                                              u16* __restrict__ xb) {
  const size_t i = ((size_t)blockIdx.x * 256 + threadIdx.x) * 8;
  float4 a = *reinterpret_cast<const float4*>(&x[i]);
  float4 b = *reinterpret_cast<const float4*>(&x[i + 4]);
  short8 v;
  v[0] = (short)f2b(a.x); v[1] = (short)f2b(a.y);
  v[2] = (short)f2b(a.z); v[3] = (short)f2b(a.w);
  v[4] = (short)f2b(b.x); v[5] = (short)f2b(b.y);
  v[6] = (short)f2b(b.z); v[7] = (short)f2b(b.w);
  *reinterpret_cast<short8*>(&xb[i]) = v;
}

// W f32 [K][N] -> Wt bf16 [N][K]
__global__ __launch_bounds__(256) void conv_w(
    const float* __restrict__ W0, const float* __restrict__ W1,
    const float* __restrict__ W2, const float* __restrict__ W3,
    u16* __restrict__ T0, u16* __restrict__ T1,
    u16* __restrict__ T2, u16* __restrict__ T3) {
  const int z = blockIdx.z;
  const float* W = z == 0 ? W0 : z == 1 ? W1 : z == 2 ? W2 : W3;
  u16* T = z == 0 ? T0 : z == 1 ? T1 : z == 2 ? T2 : T3;
  __shared__ float t[64 * 68];
  const int k0 = blockIdx.x * 64, n0 = blockIdx.y * 64, tid = threadIdx.x;
#pragma unroll
  for (int rd = 0; rd < 4; ++rd) {
    const int idx = rd * 256 + tid;
    const int r = idx >> 4, c4 = (idx & 15) * 4;
    *reinterpret_cast<float4*>(&t[r * 68 + c4]) =
        *reinterpret_cast<const float4*>(&W[(size_t)(k0 + r) * DD + n0 + c4]);
  }
  __syncthreads();
#pragma unroll
  for (int rd = 0; rd < 2; ++rd) {
    const int idx = rd * 256 + tid;
    const int rr = idx >> 3, cc = (idx & 7) * 8;
    short8 v;
#pragma unroll
    for (int e = 0; e < 8; ++e) v[e] = (short)f2b(t[(cc + e) * 68 + rr]);
    *reinterpret_cast<short8*>(&T[(size_t)(n0 + rr) * DD + k0 + cc]) = v;
  }
}

// ---------------------------------------------------------------- MFMA GEMM
// C[4096 x 1024] = A(bf16 [M][K]) @ Bt(bf16 [N][K])^T + bias.
// 128x128 tile, BK=32, 4 waves (2x2 of 64x64), reg-staged LDS w/ XOR swizzle.
// final_mode=0: z selects W/bias/out; z<2 -> bf16 row-major out; z==2 -> bf16
// transposed out [channel][token]. final_mode=1: f32 row-major out (o0).
__global__ __launch_bounds__(256, 3) void gemm_mfma(
    const u16* __restrict__ A,
    const u16* __restrict__ W0, const u16* __restrict__ W1, const u16* __restrict__ W2,
    const float* __restrict__ b0, const float* __restrict__ b1, const float* __restrict__ b2,
    void* o0, void* o1, void* o2, int final_mode) {
  const int z = blockIdx.z;
  const u16* Bt = z == 0 ? W0 : z == 1 ? W1 : W2;
  const float* bias = z == 0 ? b0 : z == 1 ? b1 : b2;
  __shared__ u16 As[128 * 32];
  __shared__ u16 Bs[128 * 32];
  const int tid = threadIdx.x;
  const int bm = blockIdx.y * 128, bn = blockIdx.x * 128;
  const int lane = tid & 63, w = tid >> 6;
  const int wr = w >> 1, wc = w & 1;
  const int lr = lane & 15, lg = lane >> 4;

  const int r0 = tid >> 2, c0 = tid & 3;
  const int r1 = r0 + 64;
  const size_t arow0 = (size_t)(bm + r0) * DD, arow1 = (size_t)(bm + r1) * DD;
  const size_t brow0 = (size_t)(bn + r0) * DD, brow1 = (size_t)(bn + r1) * DD;
  const int soff0 = r0 * 32 + ((c0 ^ ((r0 >> 1) & 3)) * 8);
  const int soff1 = r1 * 32 + ((c0 ^ ((r1 >> 1) & 3)) * 8);
  const int gcol = c0 * 8;

  const f32x4 Z4 = {0.f, 0.f, 0.f, 0.f};
  f32x4 acc[4][4];
#pragma unroll
  for (int m = 0; m < 4; ++m)
#pragma unroll
    for (int n = 0; n < 4; ++n) acc[m][n] = Z4;

  short8 ra0 = *reinterpret_cast<const short8*>(&A[arow0 + gcol]);
  short8 ra1 = *reinterpret_cast<const short8*>(&A[arow1 + gcol]);
  short8 rb0 = *reinterpret_cast<const short8*>(&Bt[brow0 + gcol]);
  short8 rb1 = *reinterpret_cast<const short8*>(&Bt[brow1 + gcol]);

  for (int k0 = 0; k0 < DD; k0 += 32) {
    __syncthreads();
    *reinterpret_cast<short8*>(&As[soff0]) = ra0;
    *reinterpret_cast<short8*>(&As[soff1]) = ra1;
    *reinterpret_cast<short8*>(&Bs[soff0]) = rb0;
    *reinterpret_cast<short8*>(&Bs[soff1]) = rb1;
    __syncthreads();
    if (k0 + 32 < DD) {
      const int g = k0 + 32 + gcol;
      ra0 = *reinterpret_cast<const short8*>(&A[arow0 + g]);
      ra1 = *reinterpret_cast<const short8*>(&A[arow1 + g]);
      rb0 = *reinterpret_cast<const short8*>(&Bt[brow0 + g]);
      rb1 = *reinterpret_cast<const short8*>(&Bt[brow1 + g]);
    }
    short8 af[4], bf[4];
#pragma unroll
    for (int m = 0; m < 4; ++m) {
      const int row = wr * 64 + m * 16 + lr;
      af[m] = *reinterpret_cast<short8*>(&As[row * 32 + ((lg ^ ((row >> 1) & 3)) * 8)]);
    }
#pragma unroll
    for (int n = 0; n < 4; ++n) {
      const int row = wc * 64 + n * 16 + lr;
      bf[n] = *reinterpret_cast<short8*>(&Bs[row * 32 + ((lg ^ ((row >> 1) & 3)) * 8)]);
    }
#pragma unroll
    for (int m = 0; m < 4; ++m)
#pragma unroll
      for (int n = 0; n < 4; ++n)
        acc[m][n] = MFMA(af[m], bf[n], acc[m][n], 0, 0, 0);
  }

  // epilogue
  const int mode = final_mode ? 2 : (z == 2 ? 1 : 0);
  u16* ob = (u16*)(z == 0 ? o0 : z == 1 ? o1 : o2);
  float* of = (float*)o0;
#pragma unroll
  for (int m = 0; m < 4; ++m) {
#pragma unroll
    for (int n = 0; n < 4; ++n) {
      const int col = bn + wc * 64 + n * 16 + lr;
      const float bv = bias[col];
      const int row0 = bm + wr * 64 + m * 16 + lg * 4;
      if (mode == 0) {
#pragma unroll
        for (int g = 0; g < 4; ++g)
          ob[(size_t)(row0 + g) * DD + col] = f2b(acc[m][n][g] + bv);
      } else if (mode == 2) {
#pragma unroll
        for (int g = 0; g < 4; ++g)
          of[(size_t)(row0 + g) * DD + col] = acc[m][n][g] + bv;
      } else {  // transposed bf16: Vt[channel][b*1024+s]
        const int bI = row0 >> 10, s0 = row0 & 1023;
        us4 pk;
#pragma unroll
        for (int g = 0; g < 4; ++g) pk[g] = f2b(acc[m][n][g] + bv);
        *reinterpret_cast<us4*>(&ob[(size_t)col * 4096 + bI * 1024 + s0]) = pk;
      }
    }
  }
}

// ---------------------------------------------------------------- attention
// Block = (i-tile 64, h, b), 256 threads = 4 waves x 16 q-rows.
// LDS tiles 64x64 bf16, 8-chunk XOR swizzle (chunk ^= row&7) -> conflict-free
// ds_read_b128 fragments. rel table f16 [64][260].
__global__ __launch_bounds__(256, 2) void attn_mfma(
    const u16* __restrict__ Qg, const u16* __restrict__ Kg,
    const u16* __restrict__ Vtg, const u16* __restrict__ remb,
    const float* __restrict__ ub, const float* __restrict__ vb,
    u16* __restrict__ AO) {
  __shared__ u16 qu_l[64 * 64];
  __shared__ u16 kk_l[64 * 64];
  __shared__ u16 vt_l[64 * 64];
  __shared__ u16 ps_l[64 * 64];  // qv during prologue, then P tile
  __shared__ _Float16 rel_l[64 * 260];

  const int tid = threadIdx.x;
  const int it = blockIdx.x, h = blockIdx.y, b = blockIdx.z;
  const int i0 = it * 64;
  const int lane = tid & 63, w = tid >> 6;
  const int lr = lane & 15, lg = lane >> 4;
  const f32x4 Z4 = {0.f, 0.f, 0.f, 0.f};

  // ---- stage qu = q+u and qv = q+v (into ps_l), swizzled
  {
    const int c = tid & 7;
    float uu[8], vv[8];
    {
      float4 a = *reinterpret_cast<const float4*>(&ub[h * 64 + c * 8]);
      float4 d = *reinterpret_cast<const float4*>(&ub[h * 64 + c * 8 + 4]);
      uu[0] = a.x; uu[1] = a.y; uu[2] = a.z; uu[3] = a.w;
      uu[4] = d.x; uu[5] = d.y; uu[6] = d.z; uu[7] = d.w;
      float4 e = *reinterpret_cast<const float4*>(&vb[h * 64 + c * 8]);
      float4 f = *reinterpret_cast<const float4*>(&vb[h * 64 + c * 8 + 4]);
      vv[0] = e.x; vv[1] = e.y; vv[2] = e.z; vv[3] = e.w;
      vv[4] = f.x; vv[5] = f.y; vv[6] = f.z; vv[7] = f.w;
    }
#pragma unroll
    for (int rd = 0; rd < 2; ++rd) {
      const int idx = rd * 256 + tid;
      const int r = idx >> 3;
      short8 q = *reinterpret_cast<const short8*>(
          &Qg[(size_t)(b * SS + i0 + r) * DD + h * 64 + c * 8]);
      short8 xu, xv;
#pragma unroll
      for (int e = 0; e < 8; ++e) {
        const float f = b2f((u16)q[e]);
        xu[e] = (short)f2b(f + uu[e]);
        xv[e] = (short)f2b(f + vv[e]);
      }
      const int cs = (c ^ (r & 7)) * 8;
      *reinterpret_cast<short8*>(&qu_l[r * 64 + cs]) = xu;
      *reinterpret_cast<short8*>(&ps_l[r * 64 + cs]) = xv;
    }
  }
  __syncthreads();

  // ---- rel phase: rel_l[i][r] = scale*(q+v)[i].remb[r], own wave rows
  {
    const int arow = w * 16 + lr;
#pragma unroll
    for (int nf = 0; nf < 17; ++nf) {
      f32x4 acc = Z4;
#pragma unroll
      for (int ks = 0; ks < 2; ++ks) {
        short8 a = *reinterpret_cast<short8*>(
            &ps_l[arow * 64 + (((ks * 4 + lg) ^ (arow & 7))) * 8]);
        short8 bbf = *reinterpret_cast<const short8*>(
            &remb[(nf * 16 + lr) * 64 + ks * 32 + lg * 8]);
        acc = MFMA(a, bbf, acc, 0, 0, 0);
      }
      const int rr = nf * 16 + lr;
      if (rr <= 256) {
#pragma unroll
        for (int g = 0; g < 4; ++g)
          rel_l[(w * 16 + lg * 4 + g) * 260 + rr] = (_Float16)(acc[g] * SCALE);
      }
    }
  }
  __syncthreads();

  float cL[4], cR[4], mrun[4], lrun[4];
  f32x4 o_acc[4];
#pragma unroll
  for (int g = 0; g < 4; ++g) {
    const int iloc = w * 16 + lg * 4 + g;
    cL[g] = (float)rel_l[iloc * 260 + 0];
    cR[g] = (float)rel_l[iloc * 260 + 256];
    mrun[g] = -3.0e38f;
    lrun[g] = 0.f;
    o_acc[g] = Z4;
  }

  const int c = tid & 7;
  const int r_a = tid >> 3, r_b = r_a + 32;

  for (int jt = 0; jt < 16; ++jt) {
    const int j0 = jt * 64;
    // issue K/V tile loads (overlap with prev tile's MFMA)
    short8 k0r = *reinterpret_cast<const short8*>(
        &Kg[(size_t)(b * SS + j0 + r_a) * DD + h * 64 + c * 8]);
    short8 k1r = *reinterpret_cast<const short8*>(
        &Kg[(size_t)(b * SS + j0 + r_b) * DD + h * 64 + c * 8]);
    short8 v0r = *reinterpret_cast<const short8*>(
        &Vtg[(size_t)(h * 64 + r_a) * 4096 + b * SS + j0 + c * 8]);
    short8 v1r = *reinterpret_cast<const short8*>(
        &Vtg[(size_t)(h * 64 + r_b) * 4096 + b * SS + j0 + c * 8]);
    __syncthreads();
    *reinterpret_cast<short8*>(&kk_l[r_a * 64 + ((c ^ (r_a & 7)) * 8)]) = k0r;
    *reinterpret_cast<short8*>(&kk_l[r_b * 64 + ((c ^ (r_b & 7)) * 8)]) = k1r;
    *reinterpret_cast<short8*>(&vt_l[r_a * 64 + ((c ^ (r_a & 7)) * 8)]) = v0r;
    *reinterpret_cast<short8*>(&vt_l[r_b * 64 + ((c ^ (r_b & 7)) * 8)]) = v1r;
    __syncthreads();

    // QK^T
    const int arow = w * 16 + lr;
    short8 aq[2];
#pragma unroll
    for (int ks = 0; ks < 2; ++ks)
      aq[ks] = *reinterpret_cast<short8*>(
          &qu_l[arow * 64 + (((ks * 4 + lg) ^ (arow & 7))) * 8]);
    f32x4 sc[4];
#pragma unroll
    for (int nf = 0; nf < 4; ++nf) {
      sc[nf] = Z4;
#pragma unroll
      for (int ks = 0; ks < 2; ++ks) {
        const int brow = nf * 16 + lr;
        short8 bbf = *reinterpret_cast<short8*>(
            &kk_l[brow * 64 + (((ks * 4 + lg) ^ (brow & 7))) * 8]);
        sc[nf] = MFMA(aq[ks], bbf, sc[nf], 0, 0, 0);
      }
    }

    // rel + online softmax. rows: iloc = w*16+lg*4+g; cols: jloc = nf*16+lr
    const int d0 = j0 - i0;
    const bool nearb = (d0 >= -128) && (d0 <= 128);
    float sv[4][4], mx[4];
#pragma unroll
    for (int g = 0; g < 4; ++g) mx[g] = -3.0e38f;
#pragma unroll
    for (int nf = 0; nf < 4; ++nf) {
#pragma unroll
      for (int g = 0; g < 4; ++g) {
        const int iloc = w * 16 + lg * 4 + g;
        const int jloc = nf * 16 + lr;
        float relv;
        if (nearb) {
          int ro = d0 + jloc - iloc;
          ro = ro < -128 ? -128 : (ro > 128 ? 128 : ro);
          relv = (float)rel_l[iloc * 260 + ro + 128];
        } else {
          relv = (d0 < 0) ? cL[g] : cR[g];
        }
        const float s = sc[nf][g] * SCALE + relv;
        sv[nf][g] = s;
        mx[g] = fmaxf(mx[g], s);
      }
    }
#pragma unroll
    for (int g = 0; g < 4; ++g) {
#pragma unroll
      for (int mk = 1; mk < 16; mk <<= 1)
        mx[g] = fmaxf(mx[g], __shfl_xor(mx[g], mk));
    }
    float al[4], rs[4];
#pragma unroll
    for (int g = 0; g < 4; ++g) {
      const float mn = fmaxf(mrun[g], mx[g]);
      al[g] = __expf(mrun[g] - mn);
      mrun[g] = mn;
      rs[g] = 0.f;
#pragma unroll
      for (int nf = 0; nf < 4; ++nf) {
        const float p = __expf(sv[nf][g] - mn);
        sv[nf][g] = p;
        rs[g] += p;
      }
    }
#pragma unroll
    for (int g = 0; g < 4; ++g) {
#pragma unroll
      for (int mk = 1; mk < 16; mk <<= 1) rs[g] += __shfl_xor(rs[g], mk);
      lrun[g] = lrun[g] * al[g] + rs[g];
    }
    // P -> LDS (bf16), rescale o
#pragma unroll
    for (int nf = 0; nf < 4; ++nf)
#pragma unroll
      for (int g = 0; g < 4; ++g) {
        const int iloc = w * 16 + lg * 4 + g;
        const int jloc = nf * 16 + lr;
        ps_l[iloc * 64 + ((jloc >> 3) ^ (iloc & 7)) * 8 + (jloc & 7)] =
            f2b(sv[nf][g]);
      }
#pragma unroll
    for (int df = 0; df < 4; ++df)
#pragma unroll
      for (int g = 0; g < 4; ++g) o_acc[df][g] *= al[g];

    // PV (own-wave rows only; no barrier needed before reads)
    short8 ap[2];
#pragma unroll
    for (int ks = 0; ks < 2; ++ks)
      ap[ks] = *reinterpret_cast<short8*>(
          &ps_l[arow * 64 + (((ks * 4 + lg) ^ (arow & 7))) * 8]);
#pragma unroll
    for (int df = 0; df < 4; ++df) {
#pragma unroll
      for (int ks = 0; ks < 2; ++ks) {
        const int brow = df * 16 + lr;
        short8 bbf = *reinterpret_cast<short8*>(
            &vt_l[brow * 64 + (((ks * 4 + lg) ^ (brow & 7))) * 8]);
        o_acc[df] = MFMA(ap[ks], bbf, o_acc[df], 0, 0, 0);
      }
    }
  }

  // epilogue: normalize, store bf16 [token][channel]
#pragma unroll
  for (int g = 0; g < 4; ++g) {
    const float inv = 1.0f / lrun[g];
    const int row = b * SS + i0 + w * 16 + lg * 4 + g;
#pragma unroll
    for (int df = 0; df < 4; ++df) {
      const int col = h * 64 + df * 16 + lr;
      AO[(size_t)row * DD + col] = f2b(o_acc[df][g] * inv);
    }
  }
}

// ---------------------------------------------------------------- launcher
extern "C" void kernel_launch(void* const* d_in, const int* in_sizes, int n_in,
                              void* d_out, int out_size, void* d_ws, size_t ws_size,
                              hipStream_t stream) {
  const float* x  = (const float*)d_in[0];
  const float* Wq = (const float*)d_in[1];
  const float* bq = (const float*)d_in[2];
  const float* Wk = (const float*)d_in[3];
  const float* bk = (const float*)d_in[4];
  const float* Wv = (const float*)d_in[5];
  const float* bv = (const float*)d_in[6];
  const float* Wo = (const float*)d_in[7];
  const float* bo = (const float*)d_in[8];
  const float* u  = (const float*)d_in[9];
  const float* v  = (const float*)d_in[10];
  float* out = (float*)d_out;

  char* p = (char*)d_ws;
  const size_t TOK = (size_t)4096 * 1024 * 2;  // 8 MB (bf16 token matrix)
  const size_t WSZ = (size_t)1024 * 1024 * 2;  // 2 MB
  u16* remb = (u16*)p; p += 272 * 64 * 2;
  u16* xb   = (u16*)p; p += TOK;
  u16* Wqt  = (u16*)p; p += WSZ;
  u16* Wkt  = (u16*)p; p += WSZ;
  u16* Wvt  = (u16*)p; p += WSZ;
  u16* Wot  = (u16*)p; p += WSZ;
  u16* Qb   = (u16*)p; p += TOK;
  u16* Kb   = (u16*)p; p += TOK;
  u16* Vt   = (u16*)p; p += TOK;
  u16* AOb  = (u16*)p; p += TOK;

  gen_remb<<<272, 64, 0, stream>>>(remb);
  conv_x<<<2048, 256, 0, stream>>>(x, xb);
  conv_w<<<dim3(16, 16, 4), 256, 0, stream>>>(Wq, Wk, Wv, Wo, Wqt, Wkt, Wvt, Wot);

  gemm_mfma<<<dim3(8, 32, 3), 256, 0, stream>>>(
      xb, Wqt, Wkt, Wvt, bq, bk, bv, Qb, Kb, Vt, 0);

  attn_mfma<<<dim3(16, 16, 4), 256, 0, stream>>>(Qb, Kb, Vt, remb, u, v, AOb);

  gemm_mfma<<<dim3(8, 32, 1), 256, 0, stream>>>(
      AOb, Wot, Wot, Wot, bo, bo, bo, out, out, out, 1);
}

// Round 7
// 159.609 us; speedup vs baseline: 6.7445x; 1.0121x over previous
//
#include <hip/hip_runtime.h>
#include <math.h>

// Transformer-XL relative-position MHSA, bf16 MFMA pipeline.
// B=4 S=1024 D=1024 H=16 HD=64 M=128.
// gen_remb -> conv_x -> conv_w -> fused QKV MFMA gemm -> knorm ->
//   MFMA flash attention (STATIC-MAX softmax: M_i = scale*|q_i+u|*max|k| +
//   relmax_i via Cauchy-Schwarz; removes per-tile shuffle reductions) ->
//   final MFMA gemm.

#define BB 4
#define SS 1024
#define DD 1024
#define HH 16
#define HDIM 64
#define SCALE 0.125f

typedef __attribute__((ext_vector_type(8))) short short8;
typedef __attribute__((ext_vector_type(4))) float f32x4;
typedef __attribute__((ext_vector_type(4))) unsigned short us4;
typedef unsigned short u16;

#define MFMA __builtin_amdgcn_mfma_f32_16x16x32_bf16

__device__ __forceinline__ float b2f(u16 v) {
  return __uint_as_float((unsigned)v << 16);
}
__device__ __forceinline__ u16 f2b(float f) {
  unsigned u = __float_as_uint(f);
  return (u16)((u + 0x7FFF + ((u >> 16) & 1)) >> 16);  // RNE
}

// ---------------------------------------------------------------- rel_emb gen
// remb bf16 [272][64]; rows 257..271 zero (pad for MFMA frag reads)
__global__ void gen_remb(u16* __restrict__ remb) {
  const int r = blockIdx.x, d = threadIdx.x;
  float val = 0.f;
  if (r < 257) {
    const int pair = d >> 1;
    const float inv_freq = exp2f(-((float)(2 * pair) / 64.0f) * 13.287712379549449f);
    const float arg = (float)(r - 128) * inv_freq;
    val = (d & 1) ? cosf(arg) : sinf(arg);
  }
  remb[r * 64 + d] = f2b(val);
}

// ---------------------------------------------------------------- conversions
__global__ __launch_bounds__(256) void conv_x(const float* __restrict__ x,
                                              u16* __restrict__ xb) {
  const size_t i = ((size_t)blockIdx.x * 256 + threadIdx.x) * 8;
  float4 a = *reinterpret_cast<const float4*>(&x[i]);
  float4 b = *reinterpret_cast<const float4*>(&x[i + 4]);
  short8 v;
  v[0] = (short)f2b(a.x); v[1] = (short)f2b(a.y);
  v[2] = (short)f2b(a.z); v[3] = (short)f2b(a.w);
  v[4] = (short)f2b(b.x); v[5] = (short)f2b(b.y);
  v[6] = (short)f2b(b.z); v[7] = (short)f2b(b.w);
  *reinterpret_cast<short8*>(&xb[i]) = v;
}

// W f32 [K][N] -> Wt bf16 [N][K]
__global__ __launch_bounds__(256) void conv_w(
    const float* __restrict__ W0, const float* __restrict__ W1,
    const float* __restrict__ W2, const float* __restrict__ W3,
    u16* __restrict__ T0, u16* __restrict__ T1,
    u16* __restrict__ T2, u16* __restrict__ T3) {
  const int z = blockIdx.z;
  const float* W = z == 0 ? W0 : z == 1 ? W1 : z == 2 ? W2 : W3;
  u16* T = z == 0 ? T0 : z == 1 ? T1 : z == 2 ? T2 : T3;
  __shared__ float t[64 * 68];
  const int k0 = blockIdx.x * 64, n0 = blockIdx.y * 64, tid = threadIdx.x;
#pragma unroll
  for (int rd = 0; rd < 4; ++rd) {
    const int idx = rd * 256 + tid;
    const int r = idx >> 4, c4 = (idx & 15) * 4;
    *reinterpret_cast<float4*>(&t[r * 68 + c4]) =
        *reinterpret_cast<const float4*>(&W[(size_t)(k0 + r) * DD + n0 + c4]);
  }
  __syncthreads();
#pragma unroll
  for (int rd = 0; rd < 2; ++rd) {
    const int idx = rd * 256 + tid;
    const int rr = idx >> 3, cc = (idx & 7) * 8;
    short8 v;
#pragma unroll
    for (int e = 0; e < 8; ++e) v[e] = (short)f2b(t[(cc + e) * 68 + rr]);
    *reinterpret_cast<short8*>(&T[(size_t)(n0 + rr) * DD + k0 + cc]) = v;
  }
}

// ---------------------------------------------------------------- K row-norm max
// kmx[b*HH+h] = max_j |K[b,j,h*64..]| (for the static softmax max bound)
__global__ __launch_bounds__(256) void knorm(const u16* __restrict__ Kg,
                                             float* __restrict__ kmx) {
  const int h = blockIdx.x, b = blockIdx.y;
  __shared__ float red[4];
  float mx = 0.f;
  for (int j = threadIdx.x; j < SS; j += 256) {
    const u16* row = &Kg[(size_t)(b * SS + j) * DD + h * 64];
    float s = 0.f;
#pragma unroll
    for (int c8 = 0; c8 < 8; ++c8) {
      short8 v = *reinterpret_cast<const short8*>(&row[c8 * 8]);
#pragma unroll
      for (int e = 0; e < 8; ++e) {
        const float f = b2f((u16)v[e]);
        s = fmaf(f, f, s);
      }
    }
    mx = fmaxf(mx, s);
  }
#pragma unroll
  for (int mk = 1; mk < 64; mk <<= 1) mx = fmaxf(mx, __shfl_xor(mx, mk));
  if ((threadIdx.x & 63) == 0) red[threadIdx.x >> 6] = mx;
  __syncthreads();
  if (threadIdx.x == 0) {
    const float m = fmaxf(fmaxf(red[0], red[1]), fmaxf(red[2], red[3]));
    kmx[b * HH + h] = sqrtf(m);
  }
}

// ---------------------------------------------------------------- MFMA GEMM
// C[4096 x 1024] = A(bf16 [M][K]) @ Bt(bf16 [N][K])^T + bias.
// 128x128 tile, BK=32, 4 waves (2x2 of 64x64), reg-staged LDS w/ XOR swizzle.
__global__ __launch_bounds__(256, 3) void gemm_mfma(
    const u16* __restrict__ A,
    const u16* __restrict__ W0, const u16* __restrict__ W1, const u16* __restrict__ W2,
    const float* __restrict__ b0, const float* __restrict__ b1, const float* __restrict__ b2,
    void* o0, void* o1, void* o2, int final_mode) {
  const int z = blockIdx.z;
  const u16* Bt = z == 0 ? W0 : z == 1 ? W1 : W2;
  const float* bias = z == 0 ? b0 : z == 1 ? b1 : b2;
  __shared__ u16 As[128 * 32];
  __shared__ u16 Bs[128 * 32];
  const int tid = threadIdx.x;
  const int bm = blockIdx.y * 128, bn = blockIdx.x * 128;
  const int lane = tid & 63, w = tid >> 6;
  const int wr = w >> 1, wc = w & 1;
  const int lr = lane & 15, lg = lane >> 4;

  const int r0 = tid >> 2, c0 = tid & 3;
  const int r1 = r0 + 64;
  const size_t arow0 = (size_t)(bm + r0) * DD, arow1 = (size_t)(bm + r1) * DD;
  const size_t brow0 = (size_t)(bn + r0) * DD, brow1 = (size_t)(bn + r1) * DD;
  const int soff0 = r0 * 32 + ((c0 ^ ((r0 >> 1) & 3)) * 8);
  const int soff1 = r1 * 32 + ((c0 ^ ((r1 >> 1) & 3)) * 8);
  const int gcol = c0 * 8;

  const f32x4 Z4 = {0.f, 0.f, 0.f, 0.f};
  f32x4 acc[4][4];
#pragma unroll
  for (int m = 0; m < 4; ++m)
#pragma unroll
    for (int n = 0; n < 4; ++n) acc[m][n] = Z4;

  short8 ra0 = *reinterpret_cast<const short8*>(&A[arow0 + gcol]);
  short8 ra1 = *reinterpret_cast<const short8*>(&A[arow1 + gcol]);
  short8 rb0 = *reinterpret_cast<const short8*>(&Bt[brow0 + gcol]);
  short8 rb1 = *reinterpret_cast<const short8*>(&Bt[brow1 + gcol]);

  for (int k0 = 0; k0 < DD; k0 += 32) {
    __syncthreads();
    *reinterpret_cast<short8*>(&As[soff0]) = ra0;
    *reinterpret_cast<short8*>(&As[soff1]) = ra1;
    *reinterpret_cast<short8*>(&Bs[soff0]) = rb0;
    *reinterpret_cast<short8*>(&Bs[soff1]) = rb1;
    __syncthreads();
    if (k0 + 32 < DD) {
      const int g = k0 + 32 + gcol;
      ra0 = *reinterpret_cast<const short8*>(&A[arow0 + g]);
      ra1 = *reinterpret_cast<const short8*>(&A[arow1 + g]);
      rb0 = *reinterpret_cast<const short8*>(&Bt[brow0 + g]);
      rb1 = *reinterpret_cast<const short8*>(&Bt[brow1 + g]);
    }
    short8 af[4], bf[4];
#pragma unroll
    for (int m = 0; m < 4; ++m) {
      const int row = wr * 64 + m * 16 + lr;
      af[m] = *reinterpret_cast<short8*>(&As[row * 32 + ((lg ^ ((row >> 1) & 3)) * 8)]);
    }
#pragma unroll
    for (int n = 0; n < 4; ++n) {
      const int row = wc * 64 + n * 16 + lr;
      bf[n] = *reinterpret_cast<short8*>(&Bs[row * 32 + ((lg ^ ((row >> 1) & 3)) * 8)]);
    }
#pragma unroll
    for (int m = 0; m < 4; ++m)
#pragma unroll
      for (int n = 0; n < 4; ++n)
        acc[m][n] = MFMA(af[m], bf[n], acc[m][n], 0, 0, 0);
  }

  // epilogue
  const int mode = final_mode ? 2 : (z == 2 ? 1 : 0);
  u16* ob = (u16*)(z == 0 ? o0 : z == 1 ? o1 : o2);
  float* of = (float*)o0;
#pragma unroll
  for (int m = 0; m < 4; ++m) {
#pragma unroll
    for (int n = 0; n < 4; ++n) {
      const int col = bn + wc * 64 + n * 16 + lr;
      const float bv = bias[col];
      const int row0 = bm + wr * 64 + m * 16 + lg * 4;
      if (mode == 0) {
#pragma unroll
        for (int g = 0; g < 4; ++g)
          ob[(size_t)(row0 + g) * DD + col] = f2b(acc[m][n][g] + bv);
      } else if (mode == 2) {
#pragma unroll
        for (int g = 0; g < 4; ++g)
          of[(size_t)(row0 + g) * DD + col] = acc[m][n][g] + bv;
      } else {  // transposed bf16: Vt[channel][b*1024+s]
        const int bI = row0 >> 10, s0 = row0 & 1023;
        us4 pk;
#pragma unroll
        for (int g = 0; g < 4; ++g) pk[g] = f2b(acc[m][n][g] + bv);
        *reinterpret_cast<us4*>(&ob[(size_t)col * 4096 + bI * 1024 + s0]) = pk;
      }
    }
  }
}

// ---------------------------------------------------------------- attention
// Block = (i-tile 64, h, b), 256 threads = 4 waves x 16 q-rows.
// STATIC-MAX streaming softmax: p = exp(s - M_i) with fixed M_i >= row max
// (Cauchy-Schwarz bound) -> no per-tile reductions, l accumulated per-thread,
// one 16-lane reduce in epilogue.
__global__ __launch_bounds__(256, 2) void attn_mfma(
    const u16* __restrict__ Qg, const u16* __restrict__ Kg,
    const u16* __restrict__ Vtg, const u16* __restrict__ remb,
    const float* __restrict__ ub, const float* __restrict__ vb,
    const float* __restrict__ kmxg, u16* __restrict__ AO) {
  __shared__ u16 qu_l[64 * 64];
  __shared__ u16 kk_l[64 * 64];
  __shared__ u16 vt_l[64 * 64];
  __shared__ u16 ps_l[64 * 64];  // qv during prologue, then P tile
  __shared__ _Float16 rel_l[64 * 260];
  __shared__ float qn_l[64];

  const int tid = threadIdx.x;
  const int it = blockIdx.x, h = blockIdx.y, b = blockIdx.z;
  const int i0 = it * 64;
  const int lane = tid & 63, w = tid >> 6;
  const int lr = lane & 15, lg = lane >> 4;
  const f32x4 Z4 = {0.f, 0.f, 0.f, 0.f};

  // ---- stage qu = q+u and qv = q+v (into ps_l), swizzled
  {
    const int c = tid & 7;
    float uu[8], vv[8];
    {
      float4 a = *reinterpret_cast<const float4*>(&ub[h * 64 + c * 8]);
      float4 d = *reinterpret_cast<const float4*>(&ub[h * 64 + c * 8 + 4]);
      uu[0] = a.x; uu[1] = a.y; uu[2] = a.z; uu[3] = a.w;
      uu[4] = d.x; uu[5] = d.y; uu[6] = d.z; uu[7] = d.w;
      float4 e = *reinterpret_cast<const float4*>(&vb[h * 64 + c * 8]);
      float4 f = *reinterpret_cast<const float4*>(&vb[h * 64 + c * 8 + 4]);
      vv[0] = e.x; vv[1] = e.y; vv[2] = e.z; vv[3] = e.w;
      vv[4] = f.x; vv[5] = f.y; vv[6] = f.z; vv[7] = f.w;
    }
#pragma unroll
    for (int rd = 0; rd < 2; ++rd) {
      const int idx = rd * 256 + tid;
      const int r = idx >> 3;
      short8 q = *reinterpret_cast<const short8*>(
          &Qg[(size_t)(b * SS + i0 + r) * DD + h * 64 + c * 8]);
      short8 xu, xv;
#pragma unroll
      for (int e = 0; e < 8; ++e) {
        const float f = b2f((u16)q[e]);
        xu[e] = (short)f2b(f + uu[e]);
        xv[e] = (short)f2b(f + vv[e]);
      }
      const int cs = (c ^ (r & 7)) * 8;
      *reinterpret_cast<short8*>(&qu_l[r * 64 + cs]) = xu;
      *reinterpret_cast<short8*>(&ps_l[r * 64 + cs]) = xv;
    }
  }
  __syncthreads();

  // ---- q-norms: |qu_i| for the static max bound (wave's own 16 rows;
  //      4 lanes per row, 16 elems each, sum across lg via shfl)
  {
    const int row = w * 16 + lr;
    float s = 0.f;
#pragma unroll
    for (int e = 0; e < 2; ++e) {
      const int cc = lg * 2 + e;
      short8 vq = *reinterpret_cast<short8*>(
          &qu_l[row * 64 + ((cc ^ (row & 7)) * 8)]);
#pragma unroll
      for (int k = 0; k < 8; ++k) {
        const float f = b2f((u16)vq[k]);
        s = fmaf(f, f, s);
      }
    }
    s += __shfl_xor(s, 16);
    s += __shfl_xor(s, 32);
    if (lg == 0) qn_l[row] = sqrtf(s);
  }

  // ---- rel phase: rel_l[i][r] = scale*(q+v)[i].remb[r]; track per-row max
  float rmx[4] = {0.f, 0.f, 0.f, 0.f};  // pad rows contribute 0 (harmless)
  {
    const int arow = w * 16 + lr;
#pragma unroll
    for (int nf = 0; nf < 17; ++nf) {
      f32x4 acc = Z4;
#pragma unroll
      for (int ks = 0; ks < 2; ++ks) {
        short8 a = *reinterpret_cast<short8*>(
            &ps_l[arow * 64 + (((ks * 4 + lg) ^ (arow & 7))) * 8]);
        short8 bbf = *reinterpret_cast<const short8*>(
            &remb[(nf * 16 + lr) * 64 + ks * 32 + lg * 8]);
        acc = MFMA(a, bbf, acc, 0, 0, 0);
      }
      const int rr = nf * 16 + lr;
#pragma unroll
      for (int g = 0; g < 4; ++g) {
        const float rv = acc[g] * SCALE;
        rmx[g] = fmaxf(rmx[g], rv);
        if (rr <= 256)
          rel_l[(w * 16 + lg * 4 + g) * 260 + rr] = (_Float16)rv;
      }
    }
    // one-time reduce across the 16 lr-lanes -> per (lg,g) row max
#pragma unroll
    for (int g = 0; g < 4; ++g)
#pragma unroll
      for (int mk = 1; mk < 16; mk <<= 1)
        rmx[g] = fmaxf(rmx[g], __shfl_xor(rmx[g], mk));
  }
  __syncthreads();

  const float kmax = kmxg[b * HH + h];
  float cL[4], cR[4], Mrow[4], lsum[4];
  f32x4 o_acc[4];
#pragma unroll
  for (int g = 0; g < 4; ++g) {
    const int iloc = w * 16 + lg * 4 + g;
    cL[g] = (float)rel_l[iloc * 260 + 0];
    cR[g] = (float)rel_l[iloc * 260 + 256];
    // M_i >= max_j s_ij : scale*|qu_i|*max|k| + relmax_i (+eps for rounding)
    Mrow[g] = fmaf(SCALE * qn_l[iloc], kmax, rmx[g] + 0.02f);
    lsum[g] = 0.f;
    o_acc[g] = Z4;
  }

  const int c = tid & 7;
  const int r_a = tid >> 3, r_b = r_a + 32;

  for (int jt = 0; jt < 16; ++jt) {
    const int j0 = jt * 64;
    // issue K/V tile loads (overlap with prev tile's MFMA)
    short8 k0r = *reinterpret_cast<const short8*>(
        &Kg[(size_t)(b * SS + j0 + r_a) * DD + h * 64 + c * 8]);
    short8 k1r = *reinterpret_cast<const short8*>(
        &Kg[(size_t)(b * SS + j0 + r_b) * DD + h * 64 + c * 8]);
    short8 v0r = *reinterpret_cast<const short8*>(
        &Vtg[(size_t)(h * 64 + r_a) * 4096 + b * SS + j0 + c * 8]);
    short8 v1r = *reinterpret_cast<const short8*>(
        &Vtg[(size_t)(h * 64 + r_b) * 4096 + b * SS + j0 + c * 8]);
    __syncthreads();
    *reinterpret_cast<short8*>(&kk_l[r_a * 64 + ((c ^ (r_a & 7)) * 8)]) = k0r;
    *reinterpret_cast<short8*>(&kk_l[r_b * 64 + ((c ^ (r_b & 7)) * 8)]) = k1r;
    *reinterpret_cast<short8*>(&vt_l[r_a * 64 + ((c ^ (r_a & 7)) * 8)]) = v0r;
    *reinterpret_cast<short8*>(&vt_l[r_b * 64 + ((c ^ (r_b & 7)) * 8)]) = v1r;
    __syncthreads();

    // QK^T
    const int arow = w * 16 + lr;
    short8 aq[2];
#pragma unroll
    for (int ks = 0; ks < 2; ++ks)
      aq[ks] = *reinterpret_cast<short8*>(
          &qu_l[arow * 64 + (((ks * 4 + lg) ^ (arow & 7))) * 8]);
    f32x4 sc[4];
#pragma unroll
    for (int nf = 0; nf < 4; ++nf) {
      sc[nf] = Z4;
#pragma unroll
      for (int ks = 0; ks < 2; ++ks) {
        const int brow = nf * 16 + lr;
        short8 bbf = *reinterpret_cast<short8*>(
            &kk_l[brow * 64 + (((ks * 4 + lg) ^ (brow & 7))) * 8]);
        sc[nf] = MFMA(aq[ks], bbf, sc[nf], 0, 0, 0);
      }
    }

    // rel add + static-max exp + P->LDS. No reductions, no rescale.
    const int d0 = j0 - i0;
    const bool nearb = (d0 >= -128) && (d0 <= 128);
#pragma unroll
    for (int nf = 0; nf < 4; ++nf) {
#pragma unroll
      for (int g = 0; g < 4; ++g) {
        const int iloc = w * 16 + lg * 4 + g;
        const int jloc = nf * 16 + lr;
        float relv;
        if (nearb) {
          int ro = d0 + jloc - iloc;
          ro = ro < -128 ? -128 : (ro > 128 ? 128 : ro);
          relv = (float)rel_l[iloc * 260 + ro + 128];
        } else {
          relv = (d0 < 0) ? cL[g] : cR[g];
        }
        const float pp = __expf(fmaf(sc[nf][g], SCALE, relv - Mrow[g]));
        lsum[g] += pp;
        ps_l[iloc * 64 + ((jloc >> 3) ^ (iloc & 7)) * 8 + (jloc & 7)] = f2b(pp);
      }
    }

    // PV (own-wave rows only; no barrier needed before reads)
    short8 ap[2];
#pragma unroll
    for (int ks = 0; ks < 2; ++ks)
      ap[ks] = *reinterpret_cast<short8*>(
          &ps_l[arow * 64 + (((ks * 4 + lg) ^ (arow & 7))) * 8]);
#pragma unroll
    for (int df = 0; df < 4; ++df) {
#pragma unroll
      for (int ks = 0; ks < 2; ++ks) {
        const int brow = df * 16 + lr;
        short8 bbf = *reinterpret_cast<short8*>(
            &vt_l[brow * 64 + (((ks * 4 + lg) ^ (brow & 7))) * 8]);
        o_acc[df] = MFMA(ap[ks], bbf, o_acc[df], 0, 0, 0);
      }
    }
  }

  // epilogue: one 16-lane l-reduce, normalize, store bf16 [token][channel]
#pragma unroll
  for (int g = 0; g < 4; ++g) {
#pragma unroll
    for (int mk = 1; mk < 16; mk <<= 1) lsum[g] += __shfl_xor(lsum[g], mk);
  }
#pragma unroll
  for (int g = 0; g < 4; ++g) {
    const float inv = 1.0f / lsum[g];
    const int row = b * SS + i0 + w * 16 + lg * 4 + g;
#pragma unroll
    for (int df = 0; df < 4; ++df) {
      const int col = h * 64 + df * 16 + lr;
      AO[(size_t)row * DD + col] = f2b(o_acc[df][g] * inv);
    }
  }
}

// ---------------------------------------------------------------- launcher
extern "C" void kernel_launch(void* const* d_in, const int* in_sizes, int n_in,
                              void* d_out, int out_size, void* d_ws, size_t ws_size,
                              hipStream_t stream) {
  const float* x  = (const float*)d_in[0];
  const float* Wq = (const float*)d_in[1];
  const float* bq = (const float*)d_in[2];
  const float* Wk = (const float*)d_in[3];
  const float* bk = (const float*)d_in[4];
  const float* Wv = (const float*)d_in[5];
  const float* bv = (const float*)d_in[6];
  const float* Wo = (const float*)d_in[7];
  const float* bo = (const float*)d_in[8];
  const float* u  = (const float*)d_in[9];
  const float* v  = (const float*)d_in[10];
  float* out = (float*)d_out;

  char* p = (char*)d_ws;
  const size_t TOK = (size_t)4096 * 1024 * 2;  // 8 MB (bf16 token matrix)
  const size_t WSZ = (size_t)1024 * 1024 * 2;  // 2 MB
  u16* remb  = (u16*)p;  p += 272 * 64 * 2;
  float* kmx = (float*)p; p += 64 * 4;
  u16* xb   = (u16*)p; p += TOK;
  u16* Wqt  = (u16*)p; p += WSZ;
  u16* Wkt  = (u16*)p; p += WSZ;
  u16* Wvt  = (u16*)p; p += WSZ;
  u16* Wot  = (u16*)p; p += WSZ;
  u16* Qb   = (u16*)p; p += TOK;
  u16* Kb   = (u16*)p; p += TOK;
  u16* Vt   = (u16*)p; p += TOK;
  u16* AOb  = (u16*)p; p += TOK;

  gen_remb<<<272, 64, 0, stream>>>(remb);
  conv_x<<<2048, 256, 0, stream>>>(x, xb);
  conv_w<<<dim3(16, 16, 4), 256, 0, stream>>>(Wq, Wk, Wv, Wo, Wqt, Wkt, Wvt, Wot);

  gemm_mfma<<<dim3(8, 32, 3), 256, 0, stream>>>(
      xb, Wqt, Wkt, Wvt, bq, bk, bv, Qb, Kb, Vt, 0);

  knorm<<<dim3(HH, BB), 256, 0, stream>>>(Kb, kmx);

  attn_mfma<<<dim3(16, 16, 4), 256, 0, stream>>>(Qb, Kb, Vt, remb, u, v, kmx, AOb);

  gemm_mfma<<<dim3(8, 32, 1), 256, 0, stream>>>(
      AOb, Wot, Wot, Wot, bo, bo, bo, out, out, out, 1);
}

// Round 9
// 123.439 us; speedup vs baseline: 8.7208x; 1.2930x over previous
//
#include <hip/hip_runtime.h>
#include <math.h>

// Transformer-XL relative-position MHSA, bf16 MFMA pipeline, v3.1.
// B=4 S=1024 D=1024 H=16 HD=64 M=128.
// Key idea: rel[i][j] = qv_i . remb[j-i] == qrot_i . e_j  (angle addition),
// so rel is FOLDED into the QK^T MFMA with inner dim 128 = [qu | qrot] x [k | e].
// (v3 bug: qrot was stored with a stray x8 -> rel overweighted 8x; fixed.)
// Clipping at |j-i|>128 handled via content-only partial accumulator + cL/cR.
// Swapped QK (mfma(K,Q)) -> P rows give b64 packed LDS writes.
// gen_et -> conv_x -> conv_w -> fused QKV gemm -> knorm -> attn -> final gemm.

#define BB 4
#define SS 1024
#define DD 1024
#define HH 16
#define HDIM 64
#define SCALE 0.125f

typedef __attribute__((ext_vector_type(8))) short short8;
typedef __attribute__((ext_vector_type(4))) float f32x4;
typedef __attribute__((ext_vector_type(4))) unsigned short us4;
typedef unsigned short u16;

#define MFMA __builtin_amdgcn_mfma_f32_16x16x32_bf16

__device__ __forceinline__ float b2f(u16 v) {
  return __uint_as_float((unsigned)v << 16);
}
__device__ __forceinline__ u16 f2b(float f) {
  unsigned u = __float_as_uint(f);
  return (u16)((u + 0x7FFF + ((u >> 16) & 1)) >> 16);  // RNE
}

// ---------------------------------------------------------------- abs sinusoid table
// Eb bf16 [1024][64]: Eb[j][2p]=sin(j*w_p), Eb[j][2p+1]=cos(j*w_p)
__global__ void gen_et(u16* __restrict__ Eb) {
  const int j = blockIdx.x, d = threadIdx.x;
  const int pair = d >> 1;
  const float inv_freq = exp2f(-((float)(2 * pair) / 64.0f) * 13.287712379549449f);
  const float arg = (float)j * inv_freq;
  const float val = (d & 1) ? cosf(arg) : sinf(arg);
  Eb[j * 64 + d] = f2b(val);
}

// ---------------------------------------------------------------- conversions
__global__ __launch_bounds__(256) void conv_x(const float* __restrict__ x,
                                              u16* __restrict__ xb) {
  const size_t i = ((size_t)blockIdx.x * 256 + threadIdx.x) * 8;
  float4 a = *reinterpret_cast<const float4*>(&x[i]);
  float4 b = *reinterpret_cast<const float4*>(&x[i + 4]);
  short8 v;
  v[0] = (short)f2b(a.x); v[1] = (short)f2b(a.y);
  v[2] = (short)f2b(a.z); v[3] = (short)f2b(a.w);
  v[4] = (short)f2b(b.x); v[5] = (short)f2b(b.y);
  v[6] = (short)f2b(b.z); v[7] = (short)f2b(b.w);
  *reinterpret_cast<short8*>(&xb[i]) = v;
}

// W f32 [K][N] -> Wt bf16 [N][K]
__global__ __launch_bounds__(256) void conv_w(
    const float* __restrict__ W0, const float* __restrict__ W1,
    const float* __restrict__ W2, const float* __restrict__ W3,
    u16* __restrict__ T0, u16* __restrict__ T1,
    u16* __restrict__ T2, u16* __restrict__ T3) {
  const int z = blockIdx.z;
  const float* W = z == 0 ? W0 : z == 1 ? W1 : z == 2 ? W2 : W3;
  u16* T = z == 0 ? T0 : z == 1 ? T1 : z == 2 ? T2 : T3;
  __shared__ float t[64 * 68];
  const int k0 = blockIdx.x * 64, n0 = blockIdx.y * 64, tid = threadIdx.x;
#pragma unroll
  for (int rd = 0; rd < 4; ++rd) {
    const int idx = rd * 256 + tid;
    const int r = idx >> 4, c4 = (idx & 15) * 4;
    *reinterpret_cast<float4*>(&t[r * 68 + c4]) =
        *reinterpret_cast<const float4*>(&W[(size_t)(k0 + r) * DD + n0 + c4]);
  }
  __syncthreads();
#pragma unroll
  for (int rd = 0; rd < 2; ++rd) {
    const int idx = rd * 256 + tid;
    const int rr = idx >> 3, cc = (idx & 7) * 8;
    short8 v;
#pragma unroll
    for (int e = 0; e < 8; ++e) v[e] = (short)f2b(t[(cc + e) * 68 + rr]);
    *reinterpret_cast<short8*>(&T[(size_t)(n0 + rr) * DD + k0 + cc]) = v;
  }
}

// ---------------------------------------------------------------- K row-norm max
__global__ __launch_bounds__(256) void knorm(const u16* __restrict__ Kg,
                                             float* __restrict__ kmx) {
  const int h = blockIdx.x, b = blockIdx.y;
  __shared__ float red[4];
  float mx = 0.f;
  for (int j = threadIdx.x; j < SS; j += 256) {
    const u16* row = &Kg[(size_t)(b * SS + j) * DD + h * 64];
    float s = 0.f;
#pragma unroll
    for (int c8 = 0; c8 < 8; ++c8) {
      short8 v = *reinterpret_cast<const short8*>(&row[c8 * 8]);
#pragma unroll
      for (int e = 0; e < 8; ++e) {
        const float f = b2f((u16)v[e]);
        s = fmaf(f, f, s);
      }
    }
    mx = fmaxf(mx, s);
  }
#pragma unroll
  for (int mk = 1; mk < 64; mk <<= 1) mx = fmaxf(mx, __shfl_xor(mx, mk));
  if ((threadIdx.x & 63) == 0) red[threadIdx.x >> 6] = mx;
  __syncthreads();
  if (threadIdx.x == 0) {
    const float m = fmaxf(fmaxf(red[0], red[1]), fmaxf(red[2], red[3]));
    kmx[b * HH + h] = sqrtf(m);
  }
}

// ---------------------------------------------------------------- MFMA GEMM
// (unchanged from round 5/7 - verified)
__global__ __launch_bounds__(256, 3) void gemm_mfma(
    const u16* __restrict__ A,
    const u16* __restrict__ W0, const u16* __restrict__ W1, const u16* __restrict__ W2,
    const float* __restrict__ b0, const float* __restrict__ b1, const float* __restrict__ b2,
    void* o0, void* o1, void* o2, int final_mode) {
  const int z = blockIdx.z;
  const u16* Bt = z == 0 ? W0 : z == 1 ? W1 : W2;
  const float* bias = z == 0 ? b0 : z == 1 ? b1 : b2;
  __shared__ u16 As[128 * 32];
  __shared__ u16 Bs[128 * 32];
  const int tid = threadIdx.x;
  const int bm = blockIdx.y * 128, bn = blockIdx.x * 128;
  const int lane = tid & 63, w = tid >> 6;
  const int wr = w >> 1, wc = w & 1;
  const int lr = lane & 15, lg = lane >> 4;

  const int r0 = tid >> 2, c0 = tid & 3;
  const int r1 = r0 + 64;
  const size_t arow0 = (size_t)(bm + r0) * DD, arow1 = (size_t)(bm + r1) * DD;
  const size_t brow0 = (size_t)(bn + r0) * DD, brow1 = (size_t)(bn + r1) * DD;
  const int soff0 = r0 * 32 + ((c0 ^ ((r0 >> 1) & 3)) * 8);
  const int soff1 = r1 * 32 + ((c0 ^ ((r1 >> 1) & 3)) * 8);
  const int gcol = c0 * 8;

  const f32x4 Z4 = {0.f, 0.f, 0.f, 0.f};
  f32x4 acc[4][4];
#pragma unroll
  for (int m = 0; m < 4; ++m)
#pragma unroll
    for (int n = 0; n < 4; ++n) acc[m][n] = Z4;

  short8 ra0 = *reinterpret_cast<const short8*>(&A[arow0 + gcol]);
  short8 ra1 = *reinterpret_cast<const short8*>(&A[arow1 + gcol]);
  short8 rb0 = *reinterpret_cast<const short8*>(&Bt[brow0 + gcol]);
  short8 rb1 = *reinterpret_cast<const short8*>(&Bt[brow1 + gcol]);

  for (int k0 = 0; k0 < DD; k0 += 32) {
    __syncthreads();
    *reinterpret_cast<short8*>(&As[soff0]) = ra0;
    *reinterpret_cast<short8*>(&As[soff1]) = ra1;
    *reinterpret_cast<short8*>(&Bs[soff0]) = rb0;
    *reinterpret_cast<short8*>(&Bs[soff1]) = rb1;
    __syncthreads();
    if (k0 + 32 < DD) {
      const int g = k0 + 32 + gcol;
      ra0 = *reinterpret_cast<const short8*>(&A[arow0 + g]);
      ra1 = *reinterpret_cast<const short8*>(&A[arow1 + g]);
      rb0 = *reinterpret_cast<const short8*>(&Bt[brow0 + g]);
      rb1 = *reinterpret_cast<const short8*>(&Bt[brow1 + g]);
    }
    short8 af[4], bf[4];
#pragma unroll
    for (int m = 0; m < 4; ++m) {
      const int row = wr * 64 + m * 16 + lr;
      af[m] = *reinterpret_cast<short8*>(&As[row * 32 + ((lg ^ ((row >> 1) & 3)) * 8)]);
    }
#pragma unroll
    for (int n = 0; n < 4; ++n) {
      const int row = wc * 64 + n * 16 + lr;
      bf[n] = *reinterpret_cast<short8*>(&Bs[row * 32 + ((lg ^ ((row >> 1) & 3)) * 8)]);
    }
#pragma unroll
    for (int m = 0; m < 4; ++m)
#pragma unroll
      for (int n = 0; n < 4; ++n)
        acc[m][n] = MFMA(af[m], bf[n], acc[m][n], 0, 0, 0);
  }

  const int mode = final_mode ? 2 : (z == 2 ? 1 : 0);
  u16* ob = (u16*)(z == 0 ? o0 : z == 1 ? o1 : o2);
  float* of = (float*)o0;
#pragma unroll
  for (int m = 0; m < 4; ++m) {
#pragma unroll
    for (int n = 0; n < 4; ++n) {
      const int col = bn + wc * 64 + n * 16 + lr;
      const float bv = bias[col];
      const int row0 = bm + wr * 64 + m * 16 + lg * 4;
      if (mode == 0) {
#pragma unroll
        for (int g = 0; g < 4; ++g)
          ob[(size_t)(row0 + g) * DD + col] = f2b(acc[m][n][g] + bv);
      } else if (mode == 2) {
#pragma unroll
        for (int g = 0; g < 4; ++g)
          of[(size_t)(row0 + g) * DD + col] = acc[m][n][g] + bv;
      } else {  // transposed bf16: Vt[channel][b*1024+s]
        const int bI = row0 >> 10, s0 = row0 & 1023;
        us4 pk;
#pragma unroll
        for (int g = 0; g < 4; ++g) pk[g] = f2b(acc[m][n][g] + bv);
        *reinterpret_cast<us4*>(&ob[(size_t)col * 4096 + bI * 1024 + s0]) = pk;
      }
    }
  }
}

// ---------------------------------------------------------------- attention v3.1
// Block = (128 q-rows, h, b); 4 waves x 32 q-rows. Inner dim 128 = [k|e] vs
// [qu|qrot] folds rel into QK MFMA. Swapped mfma(K,Q): thread holds
// S[q=nq*16+lr][k=nf*16+lg*4+g] -> b64 P writes. Static max (exact-norm bound).
__global__ __launch_bounds__(256, 3) void attn_mfma(
    const u16* __restrict__ Qg, const u16* __restrict__ Kg,
    const u16* __restrict__ Vtg, const u16* __restrict__ Eb,
    const float* __restrict__ ub, const float* __restrict__ vb,
    const float* __restrict__ kmxg, u16* __restrict__ AO) {
  __shared__ u16 kk_l[64 * 128];   // [j][128]: K-half chunks 0-7, E-half 8-15
  __shared__ u16 vt_l[64 * 64];    // [d][j]
  __shared__ u16 ps_l[128 * 64];   // [q][k]
  __shared__ float ls_l[128];

  const int tid = threadIdx.x;
  const int it = blockIdx.x, h = blockIdx.y, b = blockIdx.z;
  const int i0 = it * 128;
  const int lane = tid & 63, w = tid >> 6;
  const int lr = lane & 15, lg = lane >> 4;
  const f32x4 Z4 = {0.f, 0.f, 0.f, 0.f};

  // ---- prologue: build aq[m][ks] in registers; Mrow/cL/cR per m
  short8 aq[2][4];
  float Mrow[2], cL[2], cR[2];
  const float kmax = kmxg[b * HH + h];
#pragma unroll
  for (int m = 0; m < 2; ++m) {
    const int qpos = i0 + w * 32 + m * 16 + lr;
    const size_t qbase = (size_t)(b * SS + qpos) * DD + h * 64;
    const int iL = qpos >= 128 ? qpos - 128 : 0;
    const int iR = qpos <= 895 ? qpos + 128 : 1023;
    float nqu = 0.f, nqv = 0.f, clp = 0.f, crp = 0.f;
#pragma unroll
    for (int ks2 = 0; ks2 < 2; ++ks2) {
      const int d8 = ks2 * 32 + lg * 8;
      short8 q8 = *reinterpret_cast<const short8*>(&Qg[qbase + d8]);
      short8 e8 = *reinterpret_cast<const short8*>(&Eb[qpos * 64 + d8]);
      short8 eL8 = *reinterpret_cast<const short8*>(&Eb[iL * 64 + d8]);
      short8 eR8 = *reinterpret_cast<const short8*>(&Eb[iR * 64 + d8]);
      float us[8], vs[8];
      {
        float4 a = *reinterpret_cast<const float4*>(&ub[h * 64 + d8]);
        float4 d = *reinterpret_cast<const float4*>(&ub[h * 64 + d8 + 4]);
        us[0] = a.x; us[1] = a.y; us[2] = a.z; us[3] = a.w;
        us[4] = d.x; us[5] = d.y; us[6] = d.z; us[7] = d.w;
        float4 e = *reinterpret_cast<const float4*>(&vb[h * 64 + d8]);
        float4 f = *reinterpret_cast<const float4*>(&vb[h * 64 + d8 + 4]);
        vs[0] = e.x; vs[1] = e.y; vs[2] = e.z; vs[3] = e.w;
        vs[4] = f.x; vs[5] = f.y; vs[6] = f.z; vs[7] = f.w;
      }
      short8 xu, xr;
#pragma unroll
      for (int e = 0; e < 8; ++e) {
        const float qf = b2f((u16)q8[e]);
        xu[e] = (short)f2b(qf + us[e]);
        const float quf = b2f((u16)xu[e]);
        nqu = fmaf(quf, quf, nqu);
      }
#pragma unroll
      for (int p = 0; p < 4; ++p) {
        const float qv0 = b2f((u16)q8[2 * p]) + vs[2 * p];
        const float qv1 = b2f((u16)q8[2 * p + 1]) + vs[2 * p + 1];
        const float si = b2f((u16)e8[2 * p]), co = b2f((u16)e8[2 * p + 1]);
        const float r0 = qv0 * co + qv1 * si;     // qrot[2p]
        const float r1 = qv1 * co - qv0 * si;     // qrot[2p+1]
        xr[2 * p] = (short)f2b(r0);               // alpha = 1 (v3 had x8 bug)
        xr[2 * p + 1] = (short)f2b(r1);
        const float a0 = b2f((u16)xr[2 * p]), a1 = b2f((u16)xr[2 * p + 1]);
        nqv = fmaf(a0, a0, fmaf(a1, a1, nqv));
        clp = fmaf(a0, b2f((u16)eL8[2 * p]), fmaf(a1, b2f((u16)eL8[2 * p + 1]), clp));
        crp = fmaf(a0, b2f((u16)eR8[2 * p]), fmaf(a1, b2f((u16)eR8[2 * p + 1]), crp));
      }
      aq[m][ks2] = xu;
      aq[m][ks2 + 2] = xr;
    }
    nqu += __shfl_xor(nqu, 16); nqu += __shfl_xor(nqu, 32);
    nqv += __shfl_xor(nqv, 16); nqv += __shfl_xor(nqv, 32);
    clp += __shfl_xor(clp, 16); clp += __shfl_xor(clp, 32);
    crp += __shfl_xor(crp, 16); crp += __shfl_xor(crp, 32);
    // |e_j| <= sqrt(32)*(1+bf16 round): 0.125*5.70 = 0.7125
    Mrow[m] = 0.125f * kmax * sqrtf(nqu) + 0.7125f * sqrtf(nqv) + 0.03f;
    cL[m] = 0.125f * clp;
    cR[m] = 0.125f * crp;
  }

  float lsum[2] = {0.f, 0.f};
  f32x4 o_acc[2][4];
#pragma unroll
  for (int nq = 0; nq < 2; ++nq)
#pragma unroll
    for (int df = 0; df < 4; ++df) o_acc[nq][df] = Z4;

  const int srow = tid >> 2, sc4 = tid & 3;   // kk staging: row, chunk-group
  const int vr = tid >> 3, vc = tid & 7;      // vt staging

  for (int jt = 0; jt < 16; ++jt) {
    const int j0 = jt * 64;
    // issue global loads (overlap with previous tile's MFMA)
    const size_t kbase = (size_t)(b * SS + j0 + srow) * DD + h * 64 + sc4 * 16;
    short8 kA = *reinterpret_cast<const short8*>(&Kg[kbase]);
    short8 kB = *reinterpret_cast<const short8*>(&Kg[kbase + 8]);
    const size_t ebase = (size_t)(j0 + srow) * 64 + sc4 * 16;
    short8 eA = *reinterpret_cast<const short8*>(&Eb[ebase]);
    short8 eB = *reinterpret_cast<const short8*>(&Eb[ebase + 8]);
    short8 v0r = *reinterpret_cast<const short8*>(
        &Vtg[(size_t)(h * 64 + vr) * 4096 + b * SS + j0 + vc * 8]);
    short8 v1r = *reinterpret_cast<const short8*>(
        &Vtg[(size_t)(h * 64 + vr + 32) * 4096 + b * SS + j0 + vc * 8]);
    __syncthreads();
    {
      const int rs = srow & 15;
      *reinterpret_cast<short8*>(&kk_l[srow * 128 + (((sc4 * 2) ^ rs) * 8)]) = kA;
      *reinterpret_cast<short8*>(&kk_l[srow * 128 + (((sc4 * 2 + 1) ^ rs) * 8)]) = kB;
      *reinterpret_cast<short8*>(&kk_l[srow * 128 + (((8 + sc4 * 2) ^ rs) * 8)]) = eA;
      *reinterpret_cast<short8*>(&kk_l[srow * 128 + (((9 + sc4 * 2) ^ rs) * 8)]) = eB;
      *reinterpret_cast<short8*>(&vt_l[vr * 64 + ((vc ^ (vr & 7)) * 8)]) = v0r;
      *reinterpret_cast<short8*>(&vt_l[(vr + 32) * 64 + ((vc ^ ((vr + 32) & 7)) * 8)]) = v1r;
    }
    __syncthreads();

    const int roW = j0 - i0 - w * 32;  // wave-uniform
    if (roW < -191 || roW > 159) {
      // -------- pure far tile: content-only QK + constant rel
      const float fb0 = (roW < 0 ? cL[0] : cR[0]) - Mrow[0];
      const float fb1 = (roW < 0 ? cL[1] : cR[1]) - Mrow[1];
#pragma unroll
      for (int nf = 0; nf < 4; ++nf) {
        const int krow = nf * 16 + lr;
        short8 kf0 = *reinterpret_cast<short8*>(
            &kk_l[krow * 128 + ((lg ^ lr) * 8)]);
        short8 kf1 = *reinterpret_cast<short8*>(
            &kk_l[krow * 128 + (((4 + lg) ^ lr) * 8)]);
#pragma unroll
        for (int nq = 0; nq < 2; ++nq) {
          f32x4 s = MFMA(kf0, aq[nq][0], Z4, 0, 0, 0);
          s = MFMA(kf1, aq[nq][1], s, 0, 0, 0);
          const float base = nq == 0 ? fb0 : fb1;
          us4 pk;
#pragma unroll
          for (int g = 0; g < 4; ++g) {
            const float p = __expf(fmaf(s[g], SCALE, base));
            lsum[nq] += p;
            pk[g] = f2b(p);
          }
          const int prow = w * 32 + nq * 16 + lr;
          *reinterpret_cast<us4*>(
              &ps_l[prow * 64 + (((nf * 2 + (lg >> 1)) ^ (prow & 7)) * 8) +
                    4 * (lg & 1)]) = pk;
        }
      }
    } else {
      // -------- near tile: full 128-dim QK; per-element clamp select
#pragma unroll
      for (int nf = 0; nf < 4; ++nf) {
        const int krow = nf * 16 + lr;
        short8 kf0 = *reinterpret_cast<short8*>(
            &kk_l[krow * 128 + ((lg ^ lr) * 8)]);
        short8 kf1 = *reinterpret_cast<short8*>(
            &kk_l[krow * 128 + (((4 + lg) ^ lr) * 8)]);
        short8 kf2 = *reinterpret_cast<short8*>(
            &kk_l[krow * 128 + (((8 + lg) ^ lr) * 8)]);
        short8 kf3 = *reinterpret_cast<short8*>(
            &kk_l[krow * 128 + (((12 + lg) ^ lr) * 8)]);
#pragma unroll
        for (int nq = 0; nq < 2; ++nq) {
          f32x4 c = MFMA(kf0, aq[nq][0], Z4, 0, 0, 0);
          c = MFMA(kf1, aq[nq][1], c, 0, 0, 0);
          f32x4 t = MFMA(kf2, aq[nq][2], c, 0, 0, 0);
          t = MFMA(kf3, aq[nq][3], t, 0, 0, 0);
          const int rob = roW + nf * 16 + lg * 4 - nq * 16 - lr;
          const float bI = -Mrow[nq];
          const float bL = cL[nq] - Mrow[nq];
          const float bR = cR[nq] - Mrow[nq];
          us4 pk;
#pragma unroll
          for (int g = 0; g < 4; ++g) {
            const int ro = rob + g;
            const bool inr = (ro >= -128) && (ro <= 128);
            const float sval = inr ? t[g] : c[g];
            const float base = inr ? bI : (ro < -128 ? bL : bR);
            const float p = __expf(fmaf(sval, SCALE, base));
            lsum[nq] += p;
            pk[g] = f2b(p);
          }
          const int prow = w * 32 + nq * 16 + lr;
          *reinterpret_cast<us4*>(
              &ps_l[prow * 64 + (((nf * 2 + (lg >> 1)) ^ (prow & 7)) * 8) +
                    4 * (lg & 1)]) = pk;
        }
      }
    }

    // -------- PV: o += P . V^T-frags (ps rows are own-wave -> no barrier)
#pragma unroll
    for (int ks = 0; ks < 2; ++ks) {
      short8 ap0, ap1;
      {
        const int r0q = w * 32 + lr;
        ap0 = *reinterpret_cast<short8*>(
            &ps_l[r0q * 64 + (((ks * 4 + lg) ^ (r0q & 7)) * 8)]);
        const int r1q = w * 32 + 16 + lr;
        ap1 = *reinterpret_cast<short8*>(
            &ps_l[r1q * 64 + (((ks * 4 + lg) ^ (r1q & 7)) * 8)]);
      }
#pragma unroll
      for (int df = 0; df < 4; ++df) {
        const int vrow = df * 16 + lr;
        short8 vf = *reinterpret_cast<short8*>(
            &vt_l[vrow * 64 + (((ks * 4 + lg) ^ (vrow & 7)) * 8)]);
        o_acc[0][df] = MFMA(ap0, vf, o_acc[0][df], 0, 0, 0);
        o_acc[1][df] = MFMA(ap1, vf, o_acc[1][df], 0, 0, 0);
      }
    }
  }

  // ---- epilogue: reduce lsum over lg, redistribute via LDS, store
#pragma unroll
  for (int nq = 0; nq < 2; ++nq) {
    lsum[nq] += __shfl_xor(lsum[nq], 16);
    lsum[nq] += __shfl_xor(lsum[nq], 32);
    ls_l[w * 32 + nq * 16 + lr] = lsum[nq];
  }
#pragma unroll
  for (int nq = 0; nq < 2; ++nq) {
#pragma unroll
    for (int g = 0; g < 4; ++g) {
      const float inv = 1.0f / ls_l[w * 32 + nq * 16 + lg * 4 + g];
      const int row = b * SS + i0 + w * 32 + nq * 16 + lg * 4 + g;
#pragma unroll
      for (int df = 0; df < 4; ++df) {
        AO[(size_t)row * DD + h * 64 + df * 16 + lr] =
            f2b(o_acc[nq][df][g] * inv);
      }
    }
  }
}

// ---------------------------------------------------------------- launcher
extern "C" void kernel_launch(void* const* d_in, const int* in_sizes, int n_in,
                              void* d_out, int out_size, void* d_ws, size_t ws_size,
                              hipStream_t stream) {
  const float* x  = (const float*)d_in[0];
  const float* Wq = (const float*)d_in[1];
  const float* bq = (const float*)d_in[2];
  const float* Wk = (const float*)d_in[3];
  const float* bk = (const float*)d_in[4];
  const float* Wv = (const float*)d_in[5];
  const float* bv = (const float*)d_in[6];
  const float* Wo = (const float*)d_in[7];
  const float* bo = (const float*)d_in[8];
  const float* u  = (const float*)d_in[9];
  const float* v  = (const float*)d_in[10];
  float* out = (float*)d_out;

  char* p = (char*)d_ws;
  const size_t TOK = (size_t)4096 * 1024 * 2;  // 8 MB (bf16 token matrix)
  const size_t WSZ = (size_t)1024 * 1024 * 2;  // 2 MB
  u16* Eb    = (u16*)p;  p += (size_t)1024 * 64 * 2;
  float* kmx = (float*)p; p += 64 * 4;
  u16* xb   = (u16*)p; p += TOK;
  u16* Wqt  = (u16*)p; p += WSZ;
  u16* Wkt  = (u16*)p; p += WSZ;
  u16* Wvt  = (u16*)p; p += WSZ;
  u16* Wot  = (u16*)p; p += WSZ;
  u16* Qb   = (u16*)p; p += TOK;
  u16* Kb   = (u16*)p; p += TOK;
  u16* Vt   = (u16*)p; p += TOK;
  u16* AOb  = (u16*)p; p += TOK;

  gen_et<<<1024, 64, 0, stream>>>(Eb);
  conv_x<<<2048, 256, 0, stream>>>(x, xb);
  conv_w<<<dim3(16, 16, 4), 256, 0, stream>>>(Wq, Wk, Wv, Wo, Wqt, Wkt, Wvt, Wot);

  gemm_mfma<<<dim3(8, 32, 3), 256, 0, stream>>>(
      xb, Wqt, Wkt, Wvt, bq, bk, bv, Qb, Kb, Vt, 0);

  knorm<<<dim3(HH, BB), 256, 0, stream>>>(Kb, kmx);

  attn_mfma<<<dim3(SS / 128, HH, BB), 256, 0, stream>>>(
      Qb, Kb, Vt, Eb, u, v, kmx, AOb);

  gemm_mfma<<<dim3(8, 32, 1), 256, 0, stream>>>(
      AOb, Wot, Wot, Wot, bo, bo, bo, out, out, out, 1);
}